// Round 5
// baseline (444.662 us; speedup 1.0000x reference)
//
#include <hip/hip_runtime.h>
#include <hip/hip_bf16.h>

typedef __attribute__((ext_vector_type(8))) short bf8_t;          // 8 x bf16
typedef __attribute__((ext_vector_type(4))) float f32x4;
typedef __attribute__((ext_vector_type(4))) unsigned short u16x4;
typedef __attribute__((ext_vector_type(8))) unsigned short u16x8;
typedef unsigned long long ull;

#define DEVI static __device__ __forceinline__

DEVI unsigned short f2bf(float f) {
  union { __hip_bfloat16 h; unsigned short u; } cv;
  cv.h = __float2bfloat16(f);
  return cv.u;
}
DEVI float bf2f(unsigned short u) {
  union { __hip_bfloat16 h; unsigned short u; } cv;
  cv.u = u;
  return __bfloat162float(cv.h);
}
DEVI unsigned int pack2(float lo, float hi) {
  return (unsigned int)f2bf(lo) | ((unsigned int)f2bf(hi) << 16);
}

// ---------------- fp32 -> bf16 convert (x) ----------------
__global__ void cvt_kernel(const float* __restrict__ src, unsigned short* __restrict__ dst, int n4) {
  int i = blockIdx.x * blockDim.x + threadIdx.x;
  if (i >= n4) return;
  float4 v = reinterpret_cast<const float4*>(src)[i];
  u16x4 o;
  o[0] = f2bf(v.x); o[1] = f2bf(v.y); o[2] = f2bf(v.z); o[3] = f2bf(v.w);
  reinterpret_cast<u16x4*>(dst)[i] = o;
}

// ---------------- 4 weights in one launch ----------------
__global__ void cvt4_kernel(const float* __restrict__ s0, const float* __restrict__ s1,
                            const float* __restrict__ s2, const float* __restrict__ s3,
                            unsigned short* __restrict__ d0, unsigned short* __restrict__ d1,
                            unsigned short* __restrict__ d2, unsigned short* __restrict__ d3) {
  int sel = blockIdx.y;
  const float* s = (sel == 0) ? s0 : (sel == 1) ? s1 : (sel == 2) ? s2 : s3;
  unsigned short* d = (sel == 0) ? d0 : (sel == 1) ? d1 : (sel == 2) ? d2 : d3;
  int i = blockIdx.x * blockDim.x + threadIdx.x;
  float4 v = reinterpret_cast<const float4*>(s)[i];
  u16x4 o;
  o[0] = f2bf(v.x); o[1] = f2bf(v.y); o[2] = f2bf(v.z); o[3] = f2bf(v.w);
  reinterpret_cast<u16x4*>(d)[i] = o;
}

// ---------------- mask fp32 -> bitmask via ballot ----------------
// mask[row][j] -> bits[row][4*(j>>8) + (j&3)] bit ((j>>2)&63)
__global__ __launch_bounds__(256) void maskpack_kernel(const float* __restrict__ mask,
                                                       ull* __restrict__ bits) {
  const int w = threadIdx.x >> 6, L = threadIdx.x & 63;
  const long long row = (long long)blockIdx.x * 4 + w;
  const float* mp = mask + row * 1024 + 4 * L;
  ull* bout = bits + row * 16;
#pragma unroll
  for (int p = 0; p < 4; ++p) {
    float4 v = *reinterpret_cast<const float4*>(mp + 256 * p);
    ull b0 = __ballot(v.x != 0.f);
    ull b1 = __ballot(v.y != 0.f);
    ull b2 = __ballot(v.z != 0.f);
    ull b3 = __ballot(v.w != 0.f);
    if (L == 0) {
      bout[4 * p + 0] = b0; bout[4 * p + 1] = b1;
      bout[4 * p + 2] = b2; bout[4 * p + 3] = b3;
    }
  }
}

// ---------------- QKV GEMM; q/k -> [b,h,i,d] + normalized qn/kn; v -> vt[b,h,d,j] ----------------
__global__ __launch_bounds__(256) void qkv_gemm_kernel(
    const unsigned short* __restrict__ x_bf,
    const unsigned short* __restrict__ wq_bf, const unsigned short* __restrict__ wk_bf,
    const unsigned short* __restrict__ wv_bf,
    const float* __restrict__ bq, const float* __restrict__ bk, const float* __restrict__ bv,
    unsigned short* __restrict__ q_bf, unsigned short* __restrict__ k_bf,
    unsigned short* __restrict__ vt_bf,
    unsigned short* __restrict__ qn_bf, unsigned short* __restrict__ kn_bf)
{
  const int m0 = blockIdx.x * 64;
  const int nt = blockIdx.y;
  const int p = nt >> 3, h = nt & 7, n0 = h * 64;
  const unsigned short* W = (p == 0) ? wq_bf : (p == 1) ? wk_bf : wv_bf;
  const float* bias = (p == 0) ? bq : (p == 1) ? bk : bv;
  const int w = threadIdx.x >> 6, L = threadIdx.x & 63, c = L & 15, g = L >> 4;
  const unsigned short* arow = x_bf + (long long)(m0 + 16 * w + c) * 512 + 8 * g;
  const unsigned short* wrow = W + (long long)(n0 + c) * 512 + 8 * g;
  f32x4 acc0 = {0.f, 0.f, 0.f, 0.f}, acc1 = acc0, acc2 = acc0, acc3 = acc0;
#pragma unroll 4
  for (int kk = 0; kk < 16; ++kk) {
    bf8_t a  = *reinterpret_cast<const bf8_t*>(arow + 32 * kk);
    bf8_t b0 = *reinterpret_cast<const bf8_t*>(wrow + 32 * kk);
    bf8_t b1 = *reinterpret_cast<const bf8_t*>(wrow + 16 * 512 + 32 * kk);
    bf8_t b2 = *reinterpret_cast<const bf8_t*>(wrow + 32 * 512 + 32 * kk);
    bf8_t b3 = *reinterpret_cast<const bf8_t*>(wrow + 48 * 512 + 32 * kk);
    acc0 = __builtin_amdgcn_mfma_f32_16x16x32_bf16(a, b0, acc0, 0, 0, 0);
    acc1 = __builtin_amdgcn_mfma_f32_16x16x32_bf16(a, b1, acc1, 0, 0, 0);
    acc2 = __builtin_amdgcn_mfma_f32_16x16x32_bf16(a, b2, acc2, 0, 0, 0);
    acc3 = __builtin_amdgcn_mfma_f32_16x16x32_bf16(a, b3, acc3, 0, 0, 0);
  }
  f32x4 accs[4] = {acc0, acc1, acc2, acc3};
  unsigned short ub[4][4];
  float nacc[4] = {0.f, 0.f, 0.f, 0.f};
#pragma unroll
  for (int t = 0; t < 4; ++t) {
    float bvt = bias[n0 + 16 * t + c];
#pragma unroll
    for (int r = 0; r < 4; ++r) {
      ub[t][r] = f2bf(accs[t][r] + bvt);
      float v = bf2f(ub[t][r]);
      nacc[r] += v * v;
    }
  }
  const int bb = m0 >> 10, j0l = m0 & 1023;  // 64-aligned tile never crosses b
  if (p == 2) {
#pragma unroll
    for (int t = 0; t < 4; ++t) {
      u16x4 o;
#pragma unroll
      for (int r = 0; r < 4; ++r) o[r] = ub[t][r];
      *reinterpret_cast<u16x4*>(
          vt_bf + (((long long)(bb * 8 + h)) * 64 + 16 * t + c) * 1024 + j0l + 16 * w + 4 * g) = o;
    }
  } else {
    float irn[4];
#pragma unroll
    for (int r = 0; r < 4; ++r) {
#pragma unroll
      for (int off = 1; off < 16; off <<= 1) nacc[r] += __shfl_xor(nacc[r], off, 64);
      irn[r] = rsqrtf(nacc[r]);
    }
    unsigned short* dst = (p == 0) ? q_bf : k_bf;
    unsigned short* nrm = (p == 0) ? qn_bf : kn_bf;
#pragma unroll
    for (int t = 0; t < 4; ++t) {
#pragma unroll
      for (int r = 0; r < 4; ++r) {
        int m = m0 + 16 * w + 4 * g + r;
        int ii = m & 1023;
        dst[(((long long)(bb * 8 + h)) * 1024 + ii) * 64 + 16 * t + c] = ub[t][r];
        nrm[(long long)m * 512 + n0 + 16 * t + c] = f2bf(bf2f(ub[t][r]) * irn[r]);
      }
    }
  }
}

// ---------------- per-head attention: swapped QK^T, register softmax, reg-direct PV ----------------
#define ON 67
__global__ __launch_bounds__(256, 4) void attn_head_kernel(
    const unsigned short* __restrict__ qbf, const unsigned short* __restrict__ kbf,
    const ull* __restrict__ bits, const unsigned short* __restrict__ vt,
    float* __restrict__ attn_out, unsigned short* __restrict__ inter)
{
  __shared__ float O_lds[4][16][ON];     // 17.2 KB, padded
  __shared__ float redM[4][16], redS[4][16];
  const int i0 = blockIdx.x * 16;
  const int bh = blockIdx.y;
  const int b = bh >> 3, h = bh & 7;
  const int w = threadIdx.x >> 6, L = threadIdx.x & 63, c = L & 15, g = L >> 4;
  const int j0 = 256 * w;
  const long long bho = (long long)bh * 65536;

  // Q fragments (B operand): rows i = i0 + c
  const unsigned short* qp = qbf + bho + (i0 + c) * 64 + 8 * g;
  bf8_t qf0 = *reinterpret_cast<const bf8_t*>(qp);
  bf8_t qf1 = *reinterpret_cast<const bf8_t*>(qp + 32);

  // mask words for row i = i0+c, j in [j0, j0+256):
  // j = j0 + 16*jt + 4*g + r  ->  word 4*w + r, bit 4*jt + g
  const ull* bp = bits + ((long long)b * 1024 + i0 + c) * 16 + 4 * w;
  ull mw[4];
  {
    ulonglong2 m01 = *reinterpret_cast<const ulonglong2*>(bp);
    ulonglong2 m23 = *reinterpret_cast<const ulonglong2*>(bp + 2);
    mw[0] = m01.x; mw[1] = m01.y; mw[2] = m23.x; mw[3] = m23.y;
  }

  // swapped QK^T: sc[jt][r] = S[j = j0+16jt+4g+r][i = i0+c]
  f32x4 sc[16];
  const unsigned short* kh = kbf + bho + (long long)(j0 + c) * 64 + 8 * g;
#pragma unroll
  for (int jt = 0; jt < 16; ++jt) {
    const unsigned short* kp = kh + 1024 * jt;   // +16 rows
    f32x4 acc = {0.f, 0.f, 0.f, 0.f};
    acc = __builtin_amdgcn_mfma_f32_16x16x32_bf16(*reinterpret_cast<const bf8_t*>(kp), qf0, acc, 0, 0, 0);
    acc = __builtin_amdgcn_mfma_f32_16x16x32_bf16(*reinterpret_cast<const bf8_t*>(kp + 32), qf1, acc, 0, 0, 0);
    sc[jt] = acc;
  }

  // mask + scale + lane-local max (all 64 values belong to row i0+c)
  float rmax = -1e30f;
#pragma unroll
  for (int jt = 0; jt < 16; ++jt) {
#pragma unroll
    for (int r = 0; r < 4; ++r) {
      float lg = ((mw[r] >> (4 * jt + g)) & 1ull) ? sc[jt][r] * 0.125f
                                                  : -2.8782313662425572f; // LARGE_NEG/8
      sc[jt][r] = lg;
      rmax = fmaxf(rmax, lg);
    }
  }
  rmax = fmaxf(rmax, __shfl_xor(rmax, 16, 64));
  rmax = fmaxf(rmax, __shfl_xor(rmax, 32, 64));
  float rsum = 0.f;
#pragma unroll
  for (int jt = 0; jt < 16; ++jt) {
#pragma unroll
    for (int r = 0; r < 4; ++r) {
      float e = __expf(sc[jt][r] - rmax);
      sc[jt][r] = e;
      rsum += e;
    }
  }
  rsum += __shfl_xor(rsum, 16, 64);
  rsum += __shfl_xor(rsum, 32, 64);
  if (L < 16) { redM[w][L] = rmax; redS[w][L] = rsum; }
  __syncthreads();  // B1
  float M = fmaxf(fmaxf(redM[0][c], redM[1][c]), fmaxf(redM[2][c], redM[3][c]));
  float den = redS[0][c] * __expf(redM[0][c] - M) + redS[1][c] * __expf(redM[1][c] - M) +
              redS[2][c] * __expf(redM[2][c] - M) + redS[3][c] * __expf(redM[3][c] - M);
  float scale = __expf(rmax - M) / den;

  // attn store (reg-direct f32x4) + pack P to bf16 pairs
  unsigned int pk[32];
  float* ao = attn_out + (long long)bh * 1048576 + (long long)(i0 + c) * 1024 + j0 + 4 * g;
#pragma unroll
  for (int jt = 0; jt < 16; ++jt) {
    f32x4 pv;
#pragma unroll
    for (int r = 0; r < 4; ++r) pv[r] = sc[jt][r] * scale;
    *reinterpret_cast<f32x4*>(ao + 16 * jt) = pv;
    pk[2 * jt]     = pack2(pv[0], pv[1]);
    pk[2 * jt + 1] = pack2(pv[2], pv[3]);
  }

  // PV with permuted contraction: A-frag = own pk registers, vt loaded with matching pi
  // k = 8g+2q+s  <->  j = j0 + 32m + 16*(q>>1) + 4g + 2*(q&1) + s
  f32x4 oacc[4] = {{0.f,0.f,0.f,0.f},{0.f,0.f,0.f,0.f},{0.f,0.f,0.f,0.f},{0.f,0.f,0.f,0.f}};
  const unsigned short* vbase = vt + (long long)bh * 65536 + j0 + 4 * g;
#pragma unroll
  for (int m = 0; m < 8; ++m) {
    union { unsigned int u[4]; bf8_t v; } af;
#pragma unroll
    for (int q = 0; q < 4; ++q) af.u[q] = pk[4 * m + q];
#pragma unroll
    for (int t = 0; t < 4; ++t) {
      const unsigned short* vp = vbase + (long long)(16 * t + c) * 1024 + 32 * m;
      union { u16x4 h[2]; bf8_t v; } bf;
      bf.h[0] = *reinterpret_cast<const u16x4*>(vp);
      bf.h[1] = *reinterpret_cast<const u16x4*>(vp + 16);
      oacc[t] = __builtin_amdgcn_mfma_f32_16x16x32_bf16(af.v, bf.v, oacc[t], 0, 0, 0);
    }
  }
  // O-partial: lane (c,g) holds O[i_local = 4g+r][d = 16t+c]
#pragma unroll
  for (int t = 0; t < 4; ++t)
#pragma unroll
    for (int r = 0; r < 4; ++r)
      O_lds[w][4 * g + r][16 * t + c] = oacc[t][r];
  __syncthreads();  // B2

  // cross-wave O reduce + bf16 store to inter
  {
    const int d = threadIdx.x & 63, q = threadIdx.x >> 6;
#pragma unroll
    for (int ii = 0; ii < 4; ++ii) {
      const int i = 4 * ii + q;
      float s = O_lds[0][i][d] + O_lds[1][i][d] + O_lds[2][i][d] + O_lds[3][i][d];
      inter[((long long)b * 1024 + i0 + i) * 512 + h * 64 + d] = f2bf(s);
    }
  }
}

// ---------------- loss: cosine GEMM (qn.kn) + num/den + popcount regular ----------------
__global__ __launch_bounds__(512, 4) void loss_kernel(
    const unsigned short* __restrict__ qn, const unsigned short* __restrict__ kn,
    const ull* __restrict__ bits, float* __restrict__ partials)
{
  __shared__ float redN[8][16], redD[8][16], redP[8][16];
  const int i0 = blockIdx.x * 16;
  const int b = blockIdx.y;
  const int w = threadIdx.x >> 6, L = threadIdx.x & 63, c = L & 15, g = L >> 4;
  const int j0 = 128 * w;
  const long long rowbase = (long long)b * 1024;

  f32x4 acc[8];
#pragma unroll
  for (int jt = 0; jt < 8; ++jt) acc[jt] = f32x4{0.f, 0.f, 0.f, 0.f};
  const unsigned short* qp = qn + (rowbase + i0 + c) * 512 + 8 * g;
  const unsigned short* kp = kn + (rowbase + j0 + c) * 512 + 8 * g;
#pragma unroll 2
  for (int kc = 0; kc < 16; ++kc) {
    bf8_t a = *reinterpret_cast<const bf8_t*>(qp + 32 * kc);
#pragma unroll
    for (int jt = 0; jt < 8; ++jt) {
      bf8_t bb = *reinterpret_cast<const bf8_t*>(kp + (long long)(16 * jt) * 512 + 32 * kc);
      acc[jt] = __builtin_amdgcn_mfma_f32_16x16x32_bf16(a, bb, acc[jt], 0, 0, 0);
    }
  }

  // unswapped layout: acc[jt][r] = cos[i = i0+4g+r][j = j0+16jt+c]
  // word = 4*(j>>8) + (j&3) = 4*(w>>1) + (c&3); bit = (j>>2)&63 = 32*(w&1) + 4*jt + (c>>2)
  const int e = c & 3, csh = c >> 2, half = (w & 1) * 32;
  ull w64[4];
#pragma unroll
  for (int r = 0; r < 4; ++r)
    w64[r] = bits[(rowbase + i0 + 4 * g + r) * 16 + 4 * (w >> 1) + e];

  float num[4] = {0.f, 0.f, 0.f, 0.f}, den[4] = {0.f, 0.f, 0.f, 0.f}, pcv[4];
#pragma unroll
  for (int r = 0; r < 4; ++r)
    pcv[r] = (c < 4) ? (float)__popcll((w64[r] >> half) & 0xFFFFFFFFull) : 0.f;
#pragma unroll
  for (int jt = 0; jt < 8; ++jt) {
#pragma unroll
    for (int r = 0; r < 4; ++r) {
      float ee = __expf(acc[jt][r] * 1.25f);
      den[r] += ee;
      num[r] += ((w64[r] >> (half + 4 * jt + csh)) & 1ull) ? ee : 0.f;
    }
  }
#pragma unroll
  for (int r = 0; r < 4; ++r) {
#pragma unroll
    for (int off = 1; off < 16; off <<= 1) {
      num[r] += __shfl_xor(num[r], off, 64);
      den[r] += __shfl_xor(den[r], off, 64);
      pcv[r] += __shfl_xor(pcv[r], off, 64);
    }
  }
  if (c == 0) {
#pragma unroll
    for (int r = 0; r < 4; ++r) {
      redN[w][4 * g + r] = num[r]; redD[w][4 * g + r] = den[r]; redP[w][4 * g + r] = pcv[r];
    }
  }
  __syncthreads();
  if (w == 0) {
    float cl = 0.f, rg = 0.f;
    if (L < 16) {
      float nm = 0.f, dn = 0.f, pc = 0.f;
#pragma unroll
      for (int ww = 0; ww < 8; ++ww) { nm += redN[ww][L]; dn += redD[ww][L]; pc += redP[ww][L]; }
      cl = __logf(dn) - __logf(nm);
      rg = pc - 1.0f;
    }
#pragma unroll
    for (int off = 1; off < 64; off <<= 1) { cl += __shfl_xor(cl, off, 64); rg += __shfl_xor(rg, off, 64); }
    if (L == 0)
      partials[blockIdx.y * 64 + blockIdx.x] = cl * (1.0f / 8192.0f) + rg * (float)(0.3 / 8380416.0);
  }
}

// ---------------- out-proj GEMM: out[8192,512] = inter @ wo^T + bo (fp32 out) ----------------
__global__ __launch_bounds__(256) void outproj_gemm_kernel(
    const unsigned short* __restrict__ A, const unsigned short* __restrict__ W,
    const float* __restrict__ bias, float* __restrict__ out_f32)
{
  const int m0 = blockIdx.x * 64;
  const int n0 = blockIdx.y * 64;
  const int w = threadIdx.x >> 6, L = threadIdx.x & 63, c = L & 15, g = L >> 4;
  const unsigned short* arow = A + (long long)(m0 + 16 * w + c) * 512 + 8 * g;
  const unsigned short* wrow = W + (long long)(n0 + c) * 512 + 8 * g;
  f32x4 acc0 = {0.f, 0.f, 0.f, 0.f}, acc1 = acc0, acc2 = acc0, acc3 = acc0;
#pragma unroll 4
  for (int kk = 0; kk < 16; ++kk) {
    bf8_t a  = *reinterpret_cast<const bf8_t*>(arow + 32 * kk);
    bf8_t b0 = *reinterpret_cast<const bf8_t*>(wrow + 32 * kk);
    bf8_t b1 = *reinterpret_cast<const bf8_t*>(wrow + 16 * 512 + 32 * kk);
    bf8_t b2 = *reinterpret_cast<const bf8_t*>(wrow + 32 * 512 + 32 * kk);
    bf8_t b3 = *reinterpret_cast<const bf8_t*>(wrow + 48 * 512 + 32 * kk);
    acc0 = __builtin_amdgcn_mfma_f32_16x16x32_bf16(a, b0, acc0, 0, 0, 0);
    acc1 = __builtin_amdgcn_mfma_f32_16x16x32_bf16(a, b1, acc1, 0, 0, 0);
    acc2 = __builtin_amdgcn_mfma_f32_16x16x32_bf16(a, b2, acc2, 0, 0, 0);
    acc3 = __builtin_amdgcn_mfma_f32_16x16x32_bf16(a, b3, acc3, 0, 0, 0);
  }
  f32x4 accs[4] = {acc0, acc1, acc2, acc3};
#pragma unroll
  for (int t = 0; t < 4; ++t) {
    int n = n0 + 16 * t + c;
    float bv = bias[n];
#pragma unroll
    for (int r = 0; r < 4; ++r)
      out_f32[(long long)(m0 + 16 * w + 4 * g + r) * 512 + n] = accs[t][r] + bv;
  }
}

// ---------------- deterministic loss reduction ----------------
__global__ void loss_reduce_kernel(const float* __restrict__ partials, float* __restrict__ out) {
  int t = threadIdx.x;
  float s = partials[t] + partials[t + 256];
#pragma unroll
  for (int off = 1; off < 64; off <<= 1) s += __shfl_xor(s, off, 64);
  __shared__ float red[4];
  if ((t & 63) == 0) red[t >> 6] = s;
  __syncthreads();
  if (t == 0) out[0] = red[0] + red[1] + red[2] + red[3];
}

extern "C" void kernel_launch(void* const* d_in, const int* in_sizes, int n_in,
                              void* d_out, int out_size, void* d_ws, size_t ws_size,
                              hipStream_t stream)
{
  const float* x    = (const float*)d_in[0];
  const float* mask = (const float*)d_in[1];
  const float* wq = (const float*)d_in[2]; const float* bq = (const float*)d_in[3];
  const float* wk = (const float*)d_in[4]; const float* bk = (const float*)d_in[5];
  const float* wv = (const float*)d_in[6]; const float* bv = (const float*)d_in[7];
  const float* wo = (const float*)d_in[8]; const float* bo = (const float*)d_in[9];

  unsigned short* x_bf  = (unsigned short*)d_ws;          // reused as inter after qkv
  unsigned short* wq_bf = x_bf + 4194304;
  unsigned short* wk_bf = wq_bf + 262144;
  unsigned short* wv_bf = wk_bf + 262144;
  unsigned short* wo_bf = wv_bf + 262144;
  unsigned short* q_bf  = wo_bf + 262144;
  unsigned short* k_bf  = q_bf + 4194304;
  unsigned short* vt_bf = k_bf + 4194304;
  unsigned short* qn_bf = vt_bf + 4194304;
  unsigned short* kn_bf = qn_bf + 4194304;
  ull* bits    = (ull*)(kn_bf + 4194304);                 // 1 MB
  float* parts = (float*)(bits + 131072);                 // 512 f32
  unsigned short* inter = x_bf;

  float* out_f  = (float*)d_out;
  float* attn_o = out_f + 4194304;
  float* loss_o = attn_o + 67108864;

  cvt_kernel<<<4096, 256, 0, stream>>>(x, x_bf, 1048576);
  cvt4_kernel<<<dim3(256, 4), 256, 0, stream>>>(wq, wk, wv, wo, wq_bf, wk_bf, wv_bf, wo_bf);

  maskpack_kernel<<<2048, 256, 0, stream>>>(mask, bits);

  qkv_gemm_kernel<<<dim3(128, 24), 256, 0, stream>>>(
      x_bf, wq_bf, wk_bf, wv_bf, bq, bk, bv, q_bf, k_bf, vt_bf, qn_bf, kn_bf);

  loss_kernel<<<dim3(64, 8), 512, 0, stream>>>(qn_bf, kn_bf, bits, parts);

  attn_head_kernel<<<dim3(64, 64), 256, 0, stream>>>(
      q_bf, k_bf, bits, vt_bf, attn_o, inter);

  outproj_gemm_kernel<<<dim3(128, 8), 256, 0, stream>>>(inter, wo_bf, bo, out_f);

  loss_reduce_kernel<<<1, 256, 0, stream>>>(parts, loss_o);
}

// Round 6
// 293.584 us; speedup vs baseline: 1.5146x; 1.5146x over previous
//
#include <hip/hip_runtime.h>
#include <hip/hip_bf16.h>

typedef __attribute__((ext_vector_type(8))) short bf8_t;          // 8 x bf16
typedef __attribute__((ext_vector_type(4))) float f32x4;
typedef __attribute__((ext_vector_type(4))) unsigned short u16x4;
typedef unsigned long long ull;

#define DEVI static __device__ __forceinline__

DEVI unsigned short f2bf(float f) {
  union { __hip_bfloat16 h; unsigned short u; } cv;
  cv.h = __float2bfloat16(f);
  return cv.u;
}
DEVI float bf2f(unsigned short u) {
  union { __hip_bfloat16 h; unsigned short u; } cv;
  cv.u = u;
  return __bfloat162float(cv.h);
}
DEVI unsigned int pack2(float lo, float hi) {
  return (unsigned int)f2bf(lo) | ((unsigned int)f2bf(hi) << 16);
}

// ---------------- fp32 -> bf16 convert (x) ----------------
__global__ void cvt_kernel(const float* __restrict__ src, unsigned short* __restrict__ dst, int n4) {
  int i = blockIdx.x * blockDim.x + threadIdx.x;
  if (i >= n4) return;
  float4 v = reinterpret_cast<const float4*>(src)[i];
  u16x4 o;
  o[0] = f2bf(v.x); o[1] = f2bf(v.y); o[2] = f2bf(v.z); o[3] = f2bf(v.w);
  reinterpret_cast<u16x4*>(dst)[i] = o;
}

// ---------------- 4 weights in one launch ----------------
__global__ void cvt4_kernel(const float* __restrict__ s0, const float* __restrict__ s1,
                            const float* __restrict__ s2, const float* __restrict__ s3,
                            unsigned short* __restrict__ d0, unsigned short* __restrict__ d1,
                            unsigned short* __restrict__ d2, unsigned short* __restrict__ d3) {
  int sel = blockIdx.y;
  const float* s = (sel == 0) ? s0 : (sel == 1) ? s1 : (sel == 2) ? s2 : s3;
  unsigned short* d = (sel == 0) ? d0 : (sel == 1) ? d1 : (sel == 2) ? d2 : d3;
  int i = blockIdx.x * blockDim.x + threadIdx.x;
  float4 v = reinterpret_cast<const float4*>(s)[i];
  u16x4 o;
  o[0] = f2bf(v.x); o[1] = f2bf(v.y); o[2] = f2bf(v.z); o[3] = f2bf(v.w);
  reinterpret_cast<u16x4*>(d)[i] = o;
}

// ---------------- mask fp32 -> bitmask via ballot ----------------
// mask[row][j] -> bits[row][4*(j>>8) + (j&3)] bit ((j>>2)&63)
__global__ __launch_bounds__(256) void maskpack_kernel(const float* __restrict__ mask,
                                                       ull* __restrict__ bits) {
  const int w = threadIdx.x >> 6, L = threadIdx.x & 63;
  const long long row = (long long)blockIdx.x * 4 + w;
  const float* mp = mask + row * 1024 + 4 * L;
  ull* bout = bits + row * 16;
#pragma unroll
  for (int p = 0; p < 4; ++p) {
    float4 v = *reinterpret_cast<const float4*>(mp + 256 * p);
    ull b0 = __ballot(v.x != 0.f);
    ull b1 = __ballot(v.y != 0.f);
    ull b2 = __ballot(v.z != 0.f);
    ull b3 = __ballot(v.w != 0.f);
    if (L == 0) {
      bout[4 * p + 0] = b0; bout[4 * p + 1] = b1;
      bout[4 * p + 2] = b2; bout[4 * p + 3] = b3;
    }
  }
}

// ---------------- QKV GEMM; outputs fragment-swizzled qs/ks/vs + qns/kns ----------------
// qs/ks: per bh 65536: (i>>4)&63 tile*1024 + (d>>5)*512 + (16*((d>>3)&3)+(i&15))*8 + (d&7)
// vs:    per bh 65536: ((j>>5)*4 + (d>>4))*512 + (16*((j>>2)&3)+(d&15))*8 + 4*((j>>4)&1) + (j&3)
// qns/kns: per b 524288: ((i&1023)>>4)*8192 + (k>>5)*512 + (16*((k>>3)&3)+(i&15))*8 + (k&7), k=64h+d
__global__ __launch_bounds__(256) void qkv_gemm_kernel(
    const unsigned short* __restrict__ x_bf,
    const unsigned short* __restrict__ wq_bf, const unsigned short* __restrict__ wk_bf,
    const unsigned short* __restrict__ wv_bf,
    const float* __restrict__ bq, const float* __restrict__ bk, const float* __restrict__ bv,
    unsigned short* __restrict__ qs, unsigned short* __restrict__ ks,
    unsigned short* __restrict__ vs,
    unsigned short* __restrict__ qns, unsigned short* __restrict__ kns)
{
  const int m0 = blockIdx.x * 64;
  const int nt = blockIdx.y;
  const int p = nt >> 3, h = nt & 7, n0 = h * 64;
  const unsigned short* W = (p == 0) ? wq_bf : (p == 1) ? wk_bf : wv_bf;
  const float* bias = (p == 0) ? bq : (p == 1) ? bk : bv;
  const int w = threadIdx.x >> 6, L = threadIdx.x & 63, c = L & 15, g = L >> 4;
  const unsigned short* arow = x_bf + (long long)(m0 + 16 * w + c) * 512 + 8 * g;
  const unsigned short* wrow = W + (long long)(n0 + c) * 512 + 8 * g;
  f32x4 acc0 = {0.f, 0.f, 0.f, 0.f}, acc1 = acc0, acc2 = acc0, acc3 = acc0;
#pragma unroll 4
  for (int kk = 0; kk < 16; ++kk) {
    bf8_t a  = *reinterpret_cast<const bf8_t*>(arow + 32 * kk);
    bf8_t b0 = *reinterpret_cast<const bf8_t*>(wrow + 32 * kk);
    bf8_t b1 = *reinterpret_cast<const bf8_t*>(wrow + 16 * 512 + 32 * kk);
    bf8_t b2 = *reinterpret_cast<const bf8_t*>(wrow + 32 * 512 + 32 * kk);
    bf8_t b3 = *reinterpret_cast<const bf8_t*>(wrow + 48 * 512 + 32 * kk);
    acc0 = __builtin_amdgcn_mfma_f32_16x16x32_bf16(a, b0, acc0, 0, 0, 0);
    acc1 = __builtin_amdgcn_mfma_f32_16x16x32_bf16(a, b1, acc1, 0, 0, 0);
    acc2 = __builtin_amdgcn_mfma_f32_16x16x32_bf16(a, b2, acc2, 0, 0, 0);
    acc3 = __builtin_amdgcn_mfma_f32_16x16x32_bf16(a, b3, acc3, 0, 0, 0);
  }
  f32x4 accs[4] = {acc0, acc1, acc2, acc3};
  unsigned short ub[4][4];
  float nacc[4] = {0.f, 0.f, 0.f, 0.f};
#pragma unroll
  for (int t = 0; t < 4; ++t) {
    float bvt = bias[n0 + 16 * t + c];
#pragma unroll
    for (int r = 0; r < 4; ++r) {
      ub[t][r] = f2bf(accs[t][r] + bvt);
      float v = bf2f(ub[t][r]);
      nacc[r] += v * v;
    }
  }
  const int b = m0 >> 10;
  const int mloc = m0 & 1023;                 // 64-aligned within batch
  if (p == 2) {
    // V: token j = m0+16w+4g+r, d = 16t+c
    // mu = (mloc>>5)+(w>>1); lane' = 16g+c; elem = 4*(w&1)+r (u16x4 per t)
    const long long vbase = (long long)(b * 8 + h) * 65536 +
                            (long long)((mloc >> 5) + (w >> 1)) * 2048 +
                            (16 * g + c) * 8 + 4 * (w & 1);
#pragma unroll
    for (int t = 0; t < 4; ++t) {
      u16x4 o;
#pragma unroll
      for (int r = 0; r < 4; ++r) o[r] = ub[t][r];
      *reinterpret_cast<u16x4*>(vs + vbase + t * 512) = o;
    }
  } else {
    float irn[4];
#pragma unroll
    for (int r = 0; r < 4; ++r) {
#pragma unroll
      for (int off = 1; off < 16; off <<= 1) nacc[r] += __shfl_xor(nacc[r], off, 64);
      irn[r] = rsqrtf(nacc[r]);
    }
    unsigned short* dst = (p == 0) ? qs : ks;
    unsigned short* nrm = (p == 0) ? qns : kns;
    const long long qsb = (long long)(b * 8 + h) * 65536 + (long long)((mloc >> 4) + w) * 1024;
    const long long nsb = (long long)b * 524288 + (long long)((mloc >> 4) + w) * 8192 +
                          (long long)(2 * h) * 512;
#pragma unroll
    for (int t = 0; t < 4; ++t) {
      const int lpart = 16 * ((2 * t + (c >> 3)) & 3);
      const int hf = t >> 1;
#pragma unroll
      for (int r = 0; r < 4; ++r) {
        const int off = (lpart + 4 * g + r) * 8 + (c & 7);
        dst[qsb + hf * 512 + off] = ub[t][r];
        nrm[nsb + hf * 512 + off] = f2bf(bf2f(ub[t][r]) * irn[r]);
      }
    }
  }
}

// ---------------- per-head attention: 8 waves, swizzled frags, register softmax ----------------
#define ON 67
__global__ __launch_bounds__(512, 4) void attn_head_kernel(
    const unsigned short* __restrict__ qs, const unsigned short* __restrict__ ks,
    const ull* __restrict__ bits, const unsigned short* __restrict__ vs,
    float* __restrict__ attn_out, unsigned short* __restrict__ inter)
{
  __shared__ float O_lds[8][16][ON];     // 34.3 KB
  __shared__ float redM[8][16], redS[8][16];
  const int i0 = blockIdx.x * 16;
  const int bh = blockIdx.y;
  const int b = bh >> 3, h = bh & 7;
  const int w = threadIdx.x >> 6, L = threadIdx.x & 63, c = L & 15, g = L >> 4;
  const int j0 = 128 * w;
  const long long bho = (long long)bh * 65536;

  // Q fragment (B operand), coalesced
  const unsigned short* qp = qs + bho + (i0 >> 4) * 1024 + L * 8;
  bf8_t qf0 = *reinterpret_cast<const bf8_t*>(qp);
  bf8_t qf1 = *reinterpret_cast<const bf8_t*>(qp + 512);

  // mask: row i0+c; j = 128w+16jt+4g+r -> word 4*(w>>1)+r, bit 32*(w&1)+4*jt+g
  const ull* bp = bits + ((long long)b * 1024 + i0 + c) * 16 + 4 * (w >> 1);
  ull mw[4];
  {
    ulonglong2 m01 = *reinterpret_cast<const ulonglong2*>(bp);
    ulonglong2 m23 = *reinterpret_cast<const ulonglong2*>(bp + 2);
    mw[0] = m01.x; mw[1] = m01.y; mw[2] = m23.x; mw[3] = m23.y;
  }
  const int bitbase = 32 * (w & 1) + g;

  // swapped QK^T from swizzled tiles: sc[jt][r] = S[j = 128w+16jt+4g+r][i = i0+c]
  f32x4 sc[8];
  const unsigned short* kp = ks + bho + (long long)(8 * w) * 1024 + L * 8;
#pragma unroll
  for (int jt = 0; jt < 8; ++jt) {
    const unsigned short* kt = kp + jt * 1024;
    f32x4 acc = {0.f, 0.f, 0.f, 0.f};
    acc = __builtin_amdgcn_mfma_f32_16x16x32_bf16(*reinterpret_cast<const bf8_t*>(kt), qf0, acc, 0, 0, 0);
    acc = __builtin_amdgcn_mfma_f32_16x16x32_bf16(*reinterpret_cast<const bf8_t*>(kt + 512), qf1, acc, 0, 0, 0);
    sc[jt] = acc;
  }

  float rmax = -1e30f;
#pragma unroll
  for (int jt = 0; jt < 8; ++jt) {
#pragma unroll
    for (int r = 0; r < 4; ++r) {
      float lg = ((mw[r] >> (bitbase + 4 * jt)) & 1ull) ? sc[jt][r] * 0.125f
                                                        : -2.8782313662425572f; // LARGE_NEG/8
      sc[jt][r] = lg;
      rmax = fmaxf(rmax, lg);
    }
  }
  rmax = fmaxf(rmax, __shfl_xor(rmax, 16, 64));
  rmax = fmaxf(rmax, __shfl_xor(rmax, 32, 64));
  float rsum = 0.f;
#pragma unroll
  for (int jt = 0; jt < 8; ++jt) {
#pragma unroll
    for (int r = 0; r < 4; ++r) {
      float e = __expf(sc[jt][r] - rmax);
      sc[jt][r] = e;
      rsum += e;
    }
  }
  rsum += __shfl_xor(rsum, 16, 64);
  rsum += __shfl_xor(rsum, 32, 64);
  if (L < 16) { redM[w][L] = rmax; redS[w][L] = rsum; }
  __syncthreads();  // B1
  float M = redM[0][c], den;
#pragma unroll
  for (int ww = 1; ww < 8; ++ww) M = fmaxf(M, redM[ww][c]);
  den = 0.f;
#pragma unroll
  for (int ww = 0; ww < 8; ++ww) den += redS[ww][c] * __expf(redM[ww][c] - M);
  const float scale = __expf(rmax - M) / den;

  // attn store (reg-direct f32x4) + pack P
  unsigned int pk[16];
  float* ao = attn_out + (long long)bh * 1048576 + (long long)(i0 + c) * 1024 + j0 + 4 * g;
#pragma unroll
  for (int jt = 0; jt < 8; ++jt) {
    f32x4 pv;
#pragma unroll
    for (int r = 0; r < 4; ++r) pv[r] = sc[jt][r] * scale;
    *reinterpret_cast<f32x4*>(ao + 16 * jt) = pv;
    pk[2 * jt]     = pack2(pv[0], pv[1]);
    pk[2 * jt + 1] = pack2(pv[2], pv[3]);
  }

  // PV: A-frag = pk registers, B-frag = one coalesced 16B load from vs
  f32x4 oacc[4] = {{0.f,0.f,0.f,0.f},{0.f,0.f,0.f,0.f},{0.f,0.f,0.f,0.f},{0.f,0.f,0.f,0.f}};
  const unsigned short* vbase = vs + bho + (long long)(16 * w) * 512 + L * 8;
#pragma unroll
  for (int m = 0; m < 4; ++m) {
    union { unsigned int u[4]; bf8_t v; } af;
#pragma unroll
    for (int q = 0; q < 4; ++q) af.u[q] = pk[4 * m + q];
#pragma unroll
    for (int t = 0; t < 4; ++t) {
      bf8_t vb = *reinterpret_cast<const bf8_t*>(vbase + (4 * m + t) * 512);
      oacc[t] = __builtin_amdgcn_mfma_f32_16x16x32_bf16(af.v, vb, oacc[t], 0, 0, 0);
    }
  }
#pragma unroll
  for (int t = 0; t < 4; ++t)
#pragma unroll
    for (int r = 0; r < 4; ++r)
      O_lds[w][4 * g + r][16 * t + c] = oacc[t][r];
  __syncthreads();  // B2

  // cross-wave O reduce (8 partials) + bf16 store
  {
    const int d = threadIdx.x & 63, rw = threadIdx.x >> 6;
#pragma unroll
    for (int ii = 0; ii < 2; ++ii) {
      const int i = rw + 8 * ii;
      float s = 0.f;
#pragma unroll
      for (int ww = 0; ww < 8; ++ww) s += O_lds[ww][i][d];
      inter[((long long)b * 1024 + i0 + i) * 512 + h * 64 + d] = f2bf(s);
    }
  }
}

// ---------------- loss: cosine GEMM from swizzled qns/kns + num/den + popcount ----------------
__global__ __launch_bounds__(512, 4) void loss_kernel(
    const unsigned short* __restrict__ qns, const unsigned short* __restrict__ kns,
    const ull* __restrict__ bits, float* __restrict__ partials)
{
  __shared__ float redN[8][16], redD[8][16], redP[8][16];
  const int i0 = blockIdx.x * 16;
  const int b = blockIdx.y;
  const int w = threadIdx.x >> 6, L = threadIdx.x & 63, c = L & 15, g = L >> 4;
  const long long rowbase = (long long)b * 1024;

  f32x4 acc[8];
#pragma unroll
  for (int jt = 0; jt < 8; ++jt) acc[jt] = f32x4{0.f, 0.f, 0.f, 0.f};
  const unsigned short* qp = qns + (long long)b * 524288 + (long long)(i0 >> 4) * 8192 + L * 8;
  const unsigned short* kp = kns + (long long)b * 524288 + (long long)(8 * w) * 8192 + L * 8;
#pragma unroll 2
  for (int kc = 0; kc < 16; ++kc) {
    bf8_t a = *reinterpret_cast<const bf8_t*>(qp + kc * 512);
#pragma unroll
    for (int jt = 0; jt < 8; ++jt) {
      bf8_t bb = *reinterpret_cast<const bf8_t*>(kp + jt * 8192 + kc * 512);
      acc[jt] = __builtin_amdgcn_mfma_f32_16x16x32_bf16(a, bb, acc[jt], 0, 0, 0);
    }
  }

  // acc[jt][r] = cos[i = i0+4g+r][j = 128w+16jt+c]
  const int e = c & 3, csh = c >> 2, half = (w & 1) * 32;
  ull w64[4];
#pragma unroll
  for (int r = 0; r < 4; ++r)
    w64[r] = bits[(rowbase + i0 + 4 * g + r) * 16 + 4 * (w >> 1) + e];

  float num[4] = {0.f, 0.f, 0.f, 0.f}, den[4] = {0.f, 0.f, 0.f, 0.f}, pcv[4];
#pragma unroll
  for (int r = 0; r < 4; ++r)
    pcv[r] = (c < 4) ? (float)__popcll((w64[r] >> half) & 0xFFFFFFFFull) : 0.f;
#pragma unroll
  for (int jt = 0; jt < 8; ++jt) {
#pragma unroll
    for (int r = 0; r < 4; ++r) {
      float ee = __expf(acc[jt][r] * 1.25f);
      den[r] += ee;
      num[r] += ((w64[r] >> (half + 4 * jt + csh)) & 1ull) ? ee : 0.f;
    }
  }
#pragma unroll
  for (int r = 0; r < 4; ++r) {
#pragma unroll
    for (int off = 1; off < 16; off <<= 1) {
      num[r] += __shfl_xor(num[r], off, 64);
      den[r] += __shfl_xor(den[r], off, 64);
      pcv[r] += __shfl_xor(pcv[r], off, 64);
    }
  }
  if (c == 0) {
#pragma unroll
    for (int r = 0; r < 4; ++r) {
      redN[w][4 * g + r] = num[r]; redD[w][4 * g + r] = den[r]; redP[w][4 * g + r] = pcv[r];
    }
  }
  __syncthreads();
  if (w == 0) {
    float cl = 0.f, rg = 0.f;
    if (L < 16) {
      float nm = 0.f, dn = 0.f, pc = 0.f;
#pragma unroll
      for (int ww = 0; ww < 8; ++ww) { nm += redN[ww][L]; dn += redD[ww][L]; pc += redP[ww][L]; }
      cl = __logf(dn) - __logf(nm);
      rg = pc - 1.0f;
    }
#pragma unroll
    for (int off = 1; off < 64; off <<= 1) { cl += __shfl_xor(cl, off, 64); rg += __shfl_xor(rg, off, 64); }
    if (L == 0)
      partials[blockIdx.y * 64 + blockIdx.x] = cl * (1.0f / 8192.0f) + rg * (float)(0.3 / 8380416.0);
  }
}

// ---------------- out-proj GEMM ----------------
__global__ __launch_bounds__(256) void outproj_gemm_kernel(
    const unsigned short* __restrict__ A, const unsigned short* __restrict__ W,
    const float* __restrict__ bias, float* __restrict__ out_f32)
{
  const int m0 = blockIdx.x * 64;
  const int n0 = blockIdx.y * 64;
  const int w = threadIdx.x >> 6, L = threadIdx.x & 63, c = L & 15, g = L >> 4;
  const unsigned short* arow = A + (long long)(m0 + 16 * w + c) * 512 + 8 * g;
  const unsigned short* wrow = W + (long long)(n0 + c) * 512 + 8 * g;
  f32x4 acc0 = {0.f, 0.f, 0.f, 0.f}, acc1 = acc0, acc2 = acc0, acc3 = acc0;
#pragma unroll 4
  for (int kk = 0; kk < 16; ++kk) {
    bf8_t a  = *reinterpret_cast<const bf8_t*>(arow + 32 * kk);
    bf8_t b0 = *reinterpret_cast<const bf8_t*>(wrow + 32 * kk);
    bf8_t b1 = *reinterpret_cast<const bf8_t*>(wrow + 16 * 512 + 32 * kk);
    bf8_t b2 = *reinterpret_cast<const bf8_t*>(wrow + 32 * 512 + 32 * kk);
    bf8_t b3 = *reinterpret_cast<const bf8_t*>(wrow + 48 * 512 + 32 * kk);
    acc0 = __builtin_amdgcn_mfma_f32_16x16x32_bf16(a, b0, acc0, 0, 0, 0);
    acc1 = __builtin_amdgcn_mfma_f32_16x16x32_bf16(a, b1, acc1, 0, 0, 0);
    acc2 = __builtin_amdgcn_mfma_f32_16x16x32_bf16(a, b2, acc2, 0, 0, 0);
    acc3 = __builtin_amdgcn_mfma_f32_16x16x32_bf16(a, b3, acc3, 0, 0, 0);
  }
  f32x4 accs[4] = {acc0, acc1, acc2, acc3};
#pragma unroll
  for (int t = 0; t < 4; ++t) {
    int n = n0 + 16 * t + c;
    float bv = bias[n];
#pragma unroll
    for (int r = 0; r < 4; ++r)
      out_f32[(long long)(m0 + 16 * w + 4 * g + r) * 512 + n] = accs[t][r] + bv;
  }
}

// ---------------- deterministic loss reduction ----------------
__global__ void loss_reduce_kernel(const float* __restrict__ partials, float* __restrict__ out) {
  int t = threadIdx.x;
  float s = partials[t] + partials[t + 256];
#pragma unroll
  for (int off = 1; off < 64; off <<= 1) s += __shfl_xor(s, off, 64);
  __shared__ float red[4];
  if ((t & 63) == 0) red[t >> 6] = s;
  __syncthreads();
  if (t == 0) out[0] = red[0] + red[1] + red[2] + red[3];
}

extern "C" void kernel_launch(void* const* d_in, const int* in_sizes, int n_in,
                              void* d_out, int out_size, void* d_ws, size_t ws_size,
                              hipStream_t stream)
{
  const float* x    = (const float*)d_in[0];
  const float* mask = (const float*)d_in[1];
  const float* wq = (const float*)d_in[2]; const float* bq = (const float*)d_in[3];
  const float* wk = (const float*)d_in[4]; const float* bk = (const float*)d_in[5];
  const float* wv = (const float*)d_in[6]; const float* bv = (const float*)d_in[7];
  const float* wo = (const float*)d_in[8]; const float* bo = (const float*)d_in[9];

  unsigned short* x_bf  = (unsigned short*)d_ws;          // reused as inter after qkv
  unsigned short* wq_bf = x_bf + 4194304;
  unsigned short* wk_bf = wq_bf + 262144;
  unsigned short* wv_bf = wk_bf + 262144;
  unsigned short* wo_bf = wv_bf + 262144;
  unsigned short* qs    = wo_bf + 262144;
  unsigned short* ks    = qs + 4194304;
  unsigned short* vsb   = ks + 4194304;
  unsigned short* qns   = vsb + 4194304;
  unsigned short* kns   = qns + 4194304;
  ull* bits    = (ull*)(kns + 4194304);                   // 1 MB
  float* parts = (float*)(bits + 131072);                 // 512 f32
  unsigned short* inter = x_bf;

  float* out_f  = (float*)d_out;
  float* attn_o = out_f + 4194304;
  float* loss_o = attn_o + 67108864;

  cvt_kernel<<<4096, 256, 0, stream>>>(x, x_bf, 1048576);
  cvt4_kernel<<<dim3(256, 4), 256, 0, stream>>>(wq, wk, wv, wo, wq_bf, wk_bf, wv_bf, wo_bf);

  maskpack_kernel<<<2048, 256, 0, stream>>>(mask, bits);

  qkv_gemm_kernel<<<dim3(128, 24), 256, 0, stream>>>(
      x_bf, wq_bf, wk_bf, wv_bf, bq, bk, bv, qs, ks, vsb, qns, kns);

  loss_kernel<<<dim3(64, 8), 512, 0, stream>>>(qns, kns, bits, parts);

  attn_head_kernel<<<dim3(64, 64), 512, 0, stream>>>(
      qs, ks, bits, vsb, attn_o, inter);

  outproj_gemm_kernel<<<dim3(128, 8), 256, 0, stream>>>(inter, wo_bf, bo, out_f);

  loss_reduce_kernel<<<1, 256, 0, stream>>>(parts, loss_o);
}

// Round 7
// 288.299 us; speedup vs baseline: 1.5424x; 1.0183x over previous
//
#include <hip/hip_runtime.h>
#include <hip/hip_bf16.h>

typedef __attribute__((ext_vector_type(8))) short bf8_t;          // 8 x bf16
typedef __attribute__((ext_vector_type(4))) float f32x4;
typedef __attribute__((ext_vector_type(4))) unsigned short u16x4;
typedef unsigned long long ull;

#define DEVI static __device__ __forceinline__

DEVI unsigned short f2bf(float f) {
  union { __hip_bfloat16 h; unsigned short u; } cv;
  cv.h = __float2bfloat16(f);
  return cv.u;
}
DEVI float bf2f(unsigned short u) {
  union { __hip_bfloat16 h; unsigned short u; } cv;
  cv.u = u;
  return __bfloat162float(cv.h);
}
DEVI unsigned int pack2(float lo, float hi) {
  return (unsigned int)f2bf(lo) | ((unsigned int)f2bf(hi) << 16);
}

// ---------------- prep: maskpack (blocks 0..2047) + x cvt (2048..6143) + w cvt (6144..7167) ----------------
__global__ __launch_bounds__(256) void prep_kernel(
    const float* __restrict__ mask, const float* __restrict__ x,
    const float* __restrict__ wq, const float* __restrict__ wk,
    const float* __restrict__ wv, const float* __restrict__ wo,
    ull* __restrict__ bits, unsigned short* __restrict__ x_bf,
    unsigned short* __restrict__ wq_bf, unsigned short* __restrict__ wk_bf,
    unsigned short* __restrict__ wv_bf, unsigned short* __restrict__ wo_bf)
{
  const int bx = blockIdx.x;
  if (bx < 2048) {
    const int w = threadIdx.x >> 6, L = threadIdx.x & 63;
    const long long row = (long long)bx * 4 + w;
    const float* mp = mask + row * 1024 + 4 * L;
    ull* bout = bits + row * 16;
#pragma unroll
    for (int p = 0; p < 4; ++p) {
      float4 v = *reinterpret_cast<const float4*>(mp + 256 * p);
      ull b0 = __ballot(v.x != 0.f);
      ull b1 = __ballot(v.y != 0.f);
      ull b2 = __ballot(v.z != 0.f);
      ull b3 = __ballot(v.w != 0.f);
      if (L == 0) {
        bout[4 * p + 0] = b0; bout[4 * p + 1] = b1;
        bout[4 * p + 2] = b2; bout[4 * p + 3] = b3;
      }
    }
  } else if (bx < 6144) {
    int i = (bx - 2048) * 256 + threadIdx.x;        // 1048576 float4s
    float4 v = reinterpret_cast<const float4*>(x)[i];
    u16x4 o;
    o[0] = f2bf(v.x); o[1] = f2bf(v.y); o[2] = f2bf(v.z); o[3] = f2bf(v.w);
    reinterpret_cast<u16x4*>(x_bf)[i] = o;
  } else {
    int sel = (bx - 6144) >> 8;
    const float* s = (sel == 0) ? wq : (sel == 1) ? wk : (sel == 2) ? wv : wo;
    unsigned short* d = (sel == 0) ? wq_bf : (sel == 1) ? wk_bf : (sel == 2) ? wv_bf : wo_bf;
    int i = ((bx - 6144) & 255) * 256 + threadIdx.x;
    float4 v = reinterpret_cast<const float4*>(s)[i];
    u16x4 o;
    o[0] = f2bf(v.x); o[1] = f2bf(v.y); o[2] = f2bf(v.z); o[3] = f2bf(v.w);
    reinterpret_cast<u16x4*>(d)[i] = o;
  }
}

// ---------------- QKV GEMM; outputs fragment-swizzled qs/ks/vs + qns/kns ----------------
// qs/ks: per bh 65536: (i>>4)*1024 + (d>>5)*512 + (16*((d>>3)&3)+(i&15))*8 + (d&7)
// vs:    per bh 65536: ((j>>5)*4 + (d>>4))*512 + (16*((j>>2)&3)+(d&15))*8 + 4*((j>>4)&1) + (j&3)
// qns/kns: per b 524288: ((i&1023)>>4)*8192 + (k>>5)*512 + (16*((k>>3)&3)+(i&15))*8 + (k&7), k=64h+d
__global__ __launch_bounds__(256) void qkv_gemm_kernel(
    const unsigned short* __restrict__ x_bf,
    const unsigned short* __restrict__ wq_bf, const unsigned short* __restrict__ wk_bf,
    const unsigned short* __restrict__ wv_bf,
    const float* __restrict__ bq, const float* __restrict__ bk, const float* __restrict__ bv,
    unsigned short* __restrict__ qs, unsigned short* __restrict__ ks,
    unsigned short* __restrict__ vs,
    unsigned short* __restrict__ qns, unsigned short* __restrict__ kns)
{
  __shared__ unsigned short stage[4096];
  __shared__ float irn_lds[64];
  const int m0 = blockIdx.x * 64;
  const int nt = blockIdx.y;
  const int p = nt >> 3, h = nt & 7, n0 = h * 64;
  const unsigned short* W = (p == 0) ? wq_bf : (p == 1) ? wk_bf : wv_bf;
  const float* bias = (p == 0) ? bq : (p == 1) ? bk : bv;
  const int w = threadIdx.x >> 6, L = threadIdx.x & 63, c = L & 15, g = L >> 4;
  const unsigned short* arow = x_bf + (long long)(m0 + 16 * w + c) * 512 + 8 * g;
  const unsigned short* wrow = W + (long long)(n0 + c) * 512 + 8 * g;
  f32x4 acc0 = {0.f, 0.f, 0.f, 0.f}, acc1 = acc0, acc2 = acc0, acc3 = acc0;
#pragma unroll 4
  for (int kk = 0; kk < 16; ++kk) {
    bf8_t a  = *reinterpret_cast<const bf8_t*>(arow + 32 * kk);
    bf8_t b0 = *reinterpret_cast<const bf8_t*>(wrow + 32 * kk);
    bf8_t b1 = *reinterpret_cast<const bf8_t*>(wrow + 16 * 512 + 32 * kk);
    bf8_t b2 = *reinterpret_cast<const bf8_t*>(wrow + 32 * 512 + 32 * kk);
    bf8_t b3 = *reinterpret_cast<const bf8_t*>(wrow + 48 * 512 + 32 * kk);
    acc0 = __builtin_amdgcn_mfma_f32_16x16x32_bf16(a, b0, acc0, 0, 0, 0);
    acc1 = __builtin_amdgcn_mfma_f32_16x16x32_bf16(a, b1, acc1, 0, 0, 0);
    acc2 = __builtin_amdgcn_mfma_f32_16x16x32_bf16(a, b2, acc2, 0, 0, 0);
    acc3 = __builtin_amdgcn_mfma_f32_16x16x32_bf16(a, b3, acc3, 0, 0, 0);
  }
  f32x4 accs[4] = {acc0, acc1, acc2, acc3};
  unsigned short ub[4][4];
  float nacc[4] = {0.f, 0.f, 0.f, 0.f};
#pragma unroll
  for (int t = 0; t < 4; ++t) {
    float bvt = bias[n0 + 16 * t + c];
#pragma unroll
    for (int r = 0; r < 4; ++r) {
      ub[t][r] = f2bf(accs[t][r] + bvt);
      float v = bf2f(ub[t][r]);
      nacc[r] += v * v;
    }
  }
  const int b = m0 >> 10;
  const int mloc = m0 & 1023;
  if (p == 2) {
    const long long vbase = (long long)(b * 8 + h) * 65536 +
                            (long long)((mloc >> 5) + (w >> 1)) * 2048 +
                            (16 * g + c) * 8 + 4 * (w & 1);
#pragma unroll
    for (int t = 0; t < 4; ++t) {
      u16x4 o;
#pragma unroll
      for (int r = 0; r < 4; ++r) o[r] = ub[t][r];
      *reinterpret_cast<u16x4*>(vs + vbase + t * 512) = o;
    }
  } else {
    float irn[4];
#pragma unroll
    for (int r = 0; r < 4; ++r) {
#pragma unroll
      for (int off = 1; off < 16; off <<= 1) nacc[r] += __shfl_xor(nacc[r], off, 64);
      irn[r] = rsqrtf(nacc[r]);
    }
    if (c == 0) {
#pragma unroll
      for (int r = 0; r < 4; ++r) irn_lds[16 * w + 4 * g + r] = irn[r];
    }
    // scatter into LDS in the consumer (fragment) layout
#pragma unroll
    for (int t = 0; t < 4; ++t) {
      const int half = t >> 1;
      const int lpart = 16 * ((2 * t + (c >> 3)) & 3);
#pragma unroll
      for (int r = 0; r < 4; ++r)
        stage[w * 1024 + half * 512 + (lpart + 4 * g + r) * 8 + (c & 7)] = ub[t][r];
    }
    __syncthreads();
    unsigned short* dst = (p == 0) ? qs : ks;
    unsigned short* nrm = (p == 0) ? qns : kns;
    const long long qsb0 = (long long)(b * 8 + h) * 65536 + (long long)(mloc >> 4) * 1024;
    const long long nsb0 = (long long)b * 524288 + (long long)(mloc >> 4) * 8192 +
                           (long long)(2 * h) * 512;
#pragma unroll
    for (int pass = 0; pass < 2; ++pass) {
      const int Wd = threadIdx.x + 256 * pass;          // word index 0..511
      const int tile = Wd >> 7, lane = Wd & 63;
      const int il = tile * 16 + (Wd & 15);
      bf8_t v = *reinterpret_cast<const bf8_t*>(stage + Wd * 8);
      float f = irn_lds[il];
      *reinterpret_cast<bf8_t*>(dst + qsb0 + (long long)Wd * 8) = v;
      bf8_t nv;
#pragma unroll
      for (int e = 0; e < 8; ++e)
        nv[e] = (short)f2bf(bf2f((unsigned short)v[e]) * f);
      *reinterpret_cast<bf8_t*>(nrm + nsb0 + (long long)tile * 8192 +
                                (long long)((Wd >> 6) & 1) * 512 + (long long)lane * 8) = nv;
    }
  }
}

// ---------------- per-head attention: 32 rows/block, shared K/V loads ----------------
#define ON 67
__global__ __launch_bounds__(512, 4) void attn_head_kernel(
    const unsigned short* __restrict__ qs, const unsigned short* __restrict__ ks,
    const ull* __restrict__ bits, const unsigned short* __restrict__ vs,
    float* __restrict__ attn_out, unsigned short* __restrict__ inter)
{
  __shared__ float O_lds[8][32][ON];      // 68.6 KB
  __shared__ float redM[8][32], redS[8][32];
  const int i0 = blockIdx.x * 32;
  const int bh = blockIdx.y;
  const int b = bh >> 3, h = bh & 7;
  const int w = threadIdx.x >> 6, L = threadIdx.x & 63, c = L & 15, g = L >> 4;
  const int j0 = 128 * w;
  const long long bho = (long long)bh * 65536;

  // Q fragments for both i-tiles
  const unsigned short* qp = qs + bho + (i0 >> 4) * 1024 + L * 8;
  bf8_t qf00 = *reinterpret_cast<const bf8_t*>(qp);
  bf8_t qf01 = *reinterpret_cast<const bf8_t*>(qp + 512);
  bf8_t qf10 = *reinterpret_cast<const bf8_t*>(qp + 1024);
  bf8_t qf11 = *reinterpret_cast<const bf8_t*>(qp + 1536);

  // QK^T, K loaded once for both tiles: scU[jt][r] = S[j = 128w+16jt+4g+r][i = i0+16U+c]
  f32x4 sc0[8], sc1[8];
  const unsigned short* kp = ks + bho + (long long)(8 * w) * 1024 + L * 8;
#pragma unroll
  for (int jt = 0; jt < 8; ++jt) {
    const unsigned short* kt = kp + jt * 1024;
    bf8_t k0 = *reinterpret_cast<const bf8_t*>(kt);
    bf8_t k1 = *reinterpret_cast<const bf8_t*>(kt + 512);
    f32x4 a0 = {0.f, 0.f, 0.f, 0.f}, a1 = {0.f, 0.f, 0.f, 0.f};
    a0 = __builtin_amdgcn_mfma_f32_16x16x32_bf16(k0, qf00, a0, 0, 0, 0);
    a0 = __builtin_amdgcn_mfma_f32_16x16x32_bf16(k1, qf01, a0, 0, 0, 0);
    a1 = __builtin_amdgcn_mfma_f32_16x16x32_bf16(k0, qf10, a1, 0, 0, 0);
    a1 = __builtin_amdgcn_mfma_f32_16x16x32_bf16(k1, qf11, a1, 0, 0, 0);
    sc0[jt] = a0; sc1[jt] = a1;
  }

  const int bitbase = 32 * (w & 1) + g;
  float rmax0 = -1e30f, rsum0 = 0.f, rmax1 = -1e30f, rsum1 = 0.f;
  {
    const ull* bp = bits + ((long long)b * 1024 + i0 + c) * 16 + 4 * (w >> 1);
    ulonglong2 m01 = *reinterpret_cast<const ulonglong2*>(bp);
    ulonglong2 m23 = *reinterpret_cast<const ulonglong2*>(bp + 2);
    ull mw[4] = {m01.x, m01.y, m23.x, m23.y};
#pragma unroll
    for (int jt = 0; jt < 8; ++jt)
#pragma unroll
      for (int r = 0; r < 4; ++r) {
        float lg = ((mw[r] >> (bitbase + 4 * jt)) & 1ull) ? sc0[jt][r] * 0.125f
                                                          : -2.8782313662425572f;
        sc0[jt][r] = lg;
        rmax0 = fmaxf(rmax0, lg);
      }
    rmax0 = fmaxf(rmax0, __shfl_xor(rmax0, 16, 64));
    rmax0 = fmaxf(rmax0, __shfl_xor(rmax0, 32, 64));
#pragma unroll
    for (int jt = 0; jt < 8; ++jt)
#pragma unroll
      for (int r = 0; r < 4; ++r) {
        float e = __expf(sc0[jt][r] - rmax0);
        sc0[jt][r] = e;
        rsum0 += e;
      }
    rsum0 += __shfl_xor(rsum0, 16, 64);
    rsum0 += __shfl_xor(rsum0, 32, 64);
  }
  {
    const ull* bp = bits + ((long long)b * 1024 + i0 + 16 + c) * 16 + 4 * (w >> 1);
    ulonglong2 m01 = *reinterpret_cast<const ulonglong2*>(bp);
    ulonglong2 m23 = *reinterpret_cast<const ulonglong2*>(bp + 2);
    ull mw[4] = {m01.x, m01.y, m23.x, m23.y};
#pragma unroll
    for (int jt = 0; jt < 8; ++jt)
#pragma unroll
      for (int r = 0; r < 4; ++r) {
        float lg = ((mw[r] >> (bitbase + 4 * jt)) & 1ull) ? sc1[jt][r] * 0.125f
                                                          : -2.8782313662425572f;
        sc1[jt][r] = lg;
        rmax1 = fmaxf(rmax1, lg);
      }
    rmax1 = fmaxf(rmax1, __shfl_xor(rmax1, 16, 64));
    rmax1 = fmaxf(rmax1, __shfl_xor(rmax1, 32, 64));
#pragma unroll
    for (int jt = 0; jt < 8; ++jt)
#pragma unroll
      for (int r = 0; r < 4; ++r) {
        float e = __expf(sc1[jt][r] - rmax1);
        sc1[jt][r] = e;
        rsum1 += e;
      }
    rsum1 += __shfl_xor(rsum1, 16, 64);
    rsum1 += __shfl_xor(rsum1, 32, 64);
  }
  if (L < 16) {
    redM[w][L] = rmax0; redS[w][L] = rsum0;
    redM[w][16 + L] = rmax1; redS[w][16 + L] = rsum1;
  }
  __syncthreads();  // B1
  float scale0, scale1;
  {
    float M = redM[0][c];
#pragma unroll
    for (int ww = 1; ww < 8; ++ww) M = fmaxf(M, redM[ww][c]);
    float den = 0.f;
#pragma unroll
    for (int ww = 0; ww < 8; ++ww) den += redS[ww][c] * __expf(redM[ww][c] - M);
    scale0 = __expf(rmax0 - M) / den;
  }
  {
    float M = redM[0][16 + c];
#pragma unroll
    for (int ww = 1; ww < 8; ++ww) M = fmaxf(M, redM[ww][16 + c]);
    float den = 0.f;
#pragma unroll
    for (int ww = 0; ww < 8; ++ww) den += redS[ww][16 + c] * __expf(redM[ww][16 + c] - M);
    scale1 = __expf(rmax1 - M) / den;
  }

  // attn stores (reg-direct f32x4) + pack P per tile
  unsigned int pk0[16], pk1[16];
  {
    float* ao = attn_out + (long long)bh * 1048576 + (long long)(i0 + c) * 1024 + j0 + 4 * g;
#pragma unroll
    for (int jt = 0; jt < 8; ++jt) {
      f32x4 pv;
#pragma unroll
      for (int r = 0; r < 4; ++r) pv[r] = sc0[jt][r] * scale0;
      *reinterpret_cast<f32x4*>(ao + 16 * jt) = pv;
      pk0[2 * jt]     = pack2(pv[0], pv[1]);
      pk0[2 * jt + 1] = pack2(pv[2], pv[3]);
    }
  }
  {
    float* ao = attn_out + (long long)bh * 1048576 + (long long)(i0 + 16 + c) * 1024 + j0 + 4 * g;
#pragma unroll
    for (int jt = 0; jt < 8; ++jt) {
      f32x4 pv;
#pragma unroll
      for (int r = 0; r < 4; ++r) pv[r] = sc1[jt][r] * scale1;
      *reinterpret_cast<f32x4*>(ao + 16 * jt) = pv;
      pk1[2 * jt]     = pack2(pv[0], pv[1]);
      pk1[2 * jt + 1] = pack2(pv[2], pv[3]);
    }
  }

  // PV with V loaded once for both tiles
  f32x4 oacc0[4] = {{0.f,0.f,0.f,0.f},{0.f,0.f,0.f,0.f},{0.f,0.f,0.f,0.f},{0.f,0.f,0.f,0.f}};
  f32x4 oacc1[4] = {{0.f,0.f,0.f,0.f},{0.f,0.f,0.f,0.f},{0.f,0.f,0.f,0.f},{0.f,0.f,0.f,0.f}};
  const unsigned short* vbase = vs + bho + (long long)(16 * w) * 512 + L * 8;
#pragma unroll
  for (int m = 0; m < 4; ++m) {
    union { unsigned int u[4]; bf8_t v; } af0, af1;
#pragma unroll
    for (int q = 0; q < 4; ++q) { af0.u[q] = pk0[4 * m + q]; af1.u[q] = pk1[4 * m + q]; }
#pragma unroll
    for (int t = 0; t < 4; ++t) {
      bf8_t vb = *reinterpret_cast<const bf8_t*>(vbase + (4 * m + t) * 512);
      oacc0[t] = __builtin_amdgcn_mfma_f32_16x16x32_bf16(af0.v, vb, oacc0[t], 0, 0, 0);
      oacc1[t] = __builtin_amdgcn_mfma_f32_16x16x32_bf16(af1.v, vb, oacc1[t], 0, 0, 0);
    }
  }
#pragma unroll
  for (int t = 0; t < 4; ++t)
#pragma unroll
    for (int r = 0; r < 4; ++r) {
      O_lds[w][4 * g + r][16 * t + c] = oacc0[t][r];
      O_lds[w][16 + 4 * g + r][16 * t + c] = oacc1[t][r];
    }
  __syncthreads();  // B2

  // cross-wave O reduce (8 partials, 32 rows) + bf16 store
  {
    const int d = threadIdx.x & 63, rw = threadIdx.x >> 6;
#pragma unroll
    for (int ii = 0; ii < 4; ++ii) {
      const int i = 8 * ii + rw;
      float s = 0.f;
#pragma unroll
      for (int ww = 0; ww < 8; ++ww) s += O_lds[ww][i][d];
      inter[((long long)b * 1024 + i0 + i) * 512 + h * 64 + d] = f2bf(s);
    }
  }
}

// ---------------- loss: cosine GEMM from swizzled qns/kns + num/den + popcount ----------------
__global__ __launch_bounds__(512, 4) void loss_kernel(
    const unsigned short* __restrict__ qns, const unsigned short* __restrict__ kns,
    const ull* __restrict__ bits, float* __restrict__ partials)
{
  __shared__ float redN[8][16], redD[8][16], redP[8][16];
  const int i0 = blockIdx.x * 16;
  const int b = blockIdx.y;
  const int w = threadIdx.x >> 6, L = threadIdx.x & 63, c = L & 15, g = L >> 4;
  const long long rowbase = (long long)b * 1024;

  f32x4 acc[8];
#pragma unroll
  for (int jt = 0; jt < 8; ++jt) acc[jt] = f32x4{0.f, 0.f, 0.f, 0.f};
  const unsigned short* qp = qns + (long long)b * 524288 + (long long)(i0 >> 4) * 8192 + L * 8;
  const unsigned short* kp = kns + (long long)b * 524288 + (long long)(8 * w) * 8192 + L * 8;
#pragma unroll 2
  for (int kc = 0; kc < 16; ++kc) {
    bf8_t a = *reinterpret_cast<const bf8_t*>(qp + kc * 512);
#pragma unroll
    for (int jt = 0; jt < 8; ++jt) {
      bf8_t bb = *reinterpret_cast<const bf8_t*>(kp + jt * 8192 + kc * 512);
      acc[jt] = __builtin_amdgcn_mfma_f32_16x16x32_bf16(a, bb, acc[jt], 0, 0, 0);
    }
  }

  const int e = c & 3, csh = c >> 2, half = (w & 1) * 32;
  ull w64[4];
#pragma unroll
  for (int r = 0; r < 4; ++r)
    w64[r] = bits[(rowbase + i0 + 4 * g + r) * 16 + 4 * (w >> 1) + e];

  float num[4] = {0.f, 0.f, 0.f, 0.f}, den[4] = {0.f, 0.f, 0.f, 0.f}, pcv[4];
#pragma unroll
  for (int r = 0; r < 4; ++r)
    pcv[r] = (c < 4) ? (float)__popcll((w64[r] >> half) & 0xFFFFFFFFull) : 0.f;
#pragma unroll
  for (int jt = 0; jt < 8; ++jt) {
#pragma unroll
    for (int r = 0; r < 4; ++r) {
      float ee = __expf(acc[jt][r] * 1.25f);
      den[r] += ee;
      num[r] += ((w64[r] >> (half + 4 * jt + csh)) & 1ull) ? ee : 0.f;
    }
  }
#pragma unroll
  for (int r = 0; r < 4; ++r) {
#pragma unroll
    for (int off = 1; off < 16; off <<= 1) {
      num[r] += __shfl_xor(num[r], off, 64);
      den[r] += __shfl_xor(den[r], off, 64);
      pcv[r] += __shfl_xor(pcv[r], off, 64);
    }
  }
  if (c == 0) {
#pragma unroll
    for (int r = 0; r < 4; ++r) {
      redN[w][4 * g + r] = num[r]; redD[w][4 * g + r] = den[r]; redP[w][4 * g + r] = pcv[r];
    }
  }
  __syncthreads();
  if (w == 0) {
    float cl = 0.f, rg = 0.f;
    if (L < 16) {
      float nm = 0.f, dn = 0.f, pc = 0.f;
#pragma unroll
      for (int ww = 0; ww < 8; ++ww) { nm += redN[ww][L]; dn += redD[ww][L]; pc += redP[ww][L]; }
      cl = __logf(dn) - __logf(nm);
      rg = pc - 1.0f;
    }
#pragma unroll
    for (int off = 1; off < 64; off <<= 1) { cl += __shfl_xor(cl, off, 64); rg += __shfl_xor(rg, off, 64); }
    if (L == 0)
      partials[blockIdx.y * 64 + blockIdx.x] = cl * (1.0f / 8192.0f) + rg * (float)(0.3 / 8380416.0);
  }
}

// ---------------- out-proj GEMM ----------------
__global__ __launch_bounds__(256) void outproj_gemm_kernel(
    const unsigned short* __restrict__ A, const unsigned short* __restrict__ W,
    const float* __restrict__ bias, float* __restrict__ out_f32)
{
  const int m0 = blockIdx.x * 64;
  const int n0 = blockIdx.y * 64;
  const int w = threadIdx.x >> 6, L = threadIdx.x & 63, c = L & 15, g = L >> 4;
  const unsigned short* arow = A + (long long)(m0 + 16 * w + c) * 512 + 8 * g;
  const unsigned short* wrow = W + (long long)(n0 + c) * 512 + 8 * g;
  f32x4 acc0 = {0.f, 0.f, 0.f, 0.f}, acc1 = acc0, acc2 = acc0, acc3 = acc0;
#pragma unroll 4
  for (int kk = 0; kk < 16; ++kk) {
    bf8_t a  = *reinterpret_cast<const bf8_t*>(arow + 32 * kk);
    bf8_t b0 = *reinterpret_cast<const bf8_t*>(wrow + 32 * kk);
    bf8_t b1 = *reinterpret_cast<const bf8_t*>(wrow + 16 * 512 + 32 * kk);
    bf8_t b2 = *reinterpret_cast<const bf8_t*>(wrow + 32 * 512 + 32 * kk);
    bf8_t b3 = *reinterpret_cast<const bf8_t*>(wrow + 48 * 512 + 32 * kk);
    acc0 = __builtin_amdgcn_mfma_f32_16x16x32_bf16(a, b0, acc0, 0, 0, 0);
    acc1 = __builtin_amdgcn_mfma_f32_16x16x32_bf16(a, b1, acc1, 0, 0, 0);
    acc2 = __builtin_amdgcn_mfma_f32_16x16x32_bf16(a, b2, acc2, 0, 0, 0);
    acc3 = __builtin_amdgcn_mfma_f32_16x16x32_bf16(a, b3, acc3, 0, 0, 0);
  }
  f32x4 accs[4] = {acc0, acc1, acc2, acc3};
#pragma unroll
  for (int t = 0; t < 4; ++t) {
    int n = n0 + 16 * t + c;
    float bv = bias[n];
#pragma unroll
    for (int r = 0; r < 4; ++r)
      out_f32[(long long)(m0 + 16 * w + 4 * g + r) * 512 + n] = accs[t][r] + bv;
  }
}

// ---------------- deterministic loss reduction ----------------
__global__ void loss_reduce_kernel(const float* __restrict__ partials, float* __restrict__ out) {
  int t = threadIdx.x;
  float s = partials[t] + partials[t + 256];
#pragma unroll
  for (int off = 1; off < 64; off <<= 1) s += __shfl_xor(s, off, 64);
  __shared__ float red[4];
  if ((t & 63) == 0) red[t >> 6] = s;
  __syncthreads();
  if (t == 0) out[0] = red[0] + red[1] + red[2] + red[3];
}

extern "C" void kernel_launch(void* const* d_in, const int* in_sizes, int n_in,
                              void* d_out, int out_size, void* d_ws, size_t ws_size,
                              hipStream_t stream)
{
  const float* x    = (const float*)d_in[0];
  const float* mask = (const float*)d_in[1];
  const float* wq = (const float*)d_in[2]; const float* bq = (const float*)d_in[3];
  const float* wk = (const float*)d_in[4]; const float* bk = (const float*)d_in[5];
  const float* wv = (const float*)d_in[6]; const float* bv = (const float*)d_in[7];
  const float* wo = (const float*)d_in[8]; const float* bo = (const float*)d_in[9];

  unsigned short* x_bf  = (unsigned short*)d_ws;          // reused as inter after qkv
  unsigned short* wq_bf = x_bf + 4194304;
  unsigned short* wk_bf = wq_bf + 262144;
  unsigned short* wv_bf = wk_bf + 262144;
  unsigned short* wo_bf = wv_bf + 262144;
  unsigned short* qs    = wo_bf + 262144;
  unsigned short* ks    = qs + 4194304;
  unsigned short* vsb   = ks + 4194304;
  unsigned short* qns   = vsb + 4194304;
  unsigned short* kns   = qns + 4194304;
  ull* bits    = (ull*)(kns + 4194304);                   // 1 MB
  float* parts = (float*)(bits + 131072);                 // 512 f32
  unsigned short* inter = x_bf;

  float* out_f  = (float*)d_out;
  float* attn_o = out_f + 4194304;
  float* loss_o = attn_o + 67108864;

  prep_kernel<<<7168, 256, 0, stream>>>(mask, x, wq, wk, wv, wo,
                                        bits, x_bf, wq_bf, wk_bf, wv_bf, wo_bf);

  qkv_gemm_kernel<<<dim3(128, 24), 256, 0, stream>>>(
      x_bf, wq_bf, wk_bf, wv_bf, bq, bk, bv, qs, ks, vsb, qns, kns);

  loss_kernel<<<dim3(64, 8), 512, 0, stream>>>(qns, kns, bits, parts);

  attn_head_kernel<<<dim3(32, 64), 512, 0, stream>>>(
      qs, ks, bits, vsb, attn_o, inter);

  outproj_gemm_kernel<<<dim3(128, 8), 256, 0, stream>>>(inter, wo_bf, bo, out_f);

  loss_reduce_kernel<<<1, 256, 0, stream>>>(parts, loss_o);
}